// Round 2
// baseline (400.059 us; speedup 1.0000x reference)
//
#include <hip/hip_runtime.h>
#include <hip/hip_bf16.h>
#include <stdint.h>

#define EPS 1e-8f

typedef __attribute__((ext_vector_type(8))) short bf16x8;
typedef __attribute__((ext_vector_type(4))) float f32x4;
typedef unsigned long long u64;
typedef unsigned int u32;

constexpr int SEQ = 200;
constexpr int B_  = 1024;    // batch
constexpr int D_  = 300;     // embedding dim
constexpr int DP  = 320;     // K padded
constexpr int NT  = 100000;  // train rows
constexpr int BM = 256, BN = 128, BK = 64;
constexpr int NSTRIP = 784;            // N strips (128 wide), multiple of 8
constexpr int NTP = NSTRIP * BN;       // 100352 padded rows
constexpr int POOL_BLOCKS = B_;        // 1024
constexpr int TN_BLOCKS = (NTP + 9) / 10;  // 10036 (10 rows/block @ 640 thr)
constexpr int CAND_MAX = 8192;
constexpr int RESCORE_BLOCKS = 2048;
#define MARGIN 2e-3f

__device__ __forceinline__ unsigned short f2bf(float f) {   // RNE
    u32 b = __float_as_uint(f);
    return (unsigned short)((b + 0x7fffu + ((b >> 16) & 1u)) >> 16);
}
__device__ __forceinline__ u32 simkey(float s) {            // order-preserving
    u32 b = __float_as_uint(s);
    return (b & 0x80000000u) ? ~b : (b | 0x80000000u);
}
__device__ __forceinline__ void gload_lds16(const void* g, void* l) {
    __builtin_amdgcn_global_load_lds(
        (const __attribute__((address_space(1))) unsigned int*)g,
        (__attribute__((address_space(3))) unsigned int*)l, 16, 0, 0);
}

// ---------------------------------------------------------------------------
// K1 "prep": fused pool (blocks 0..1023) + tnorm/convert (rest), 640 thr.
// R2: exact R0 structure (pool blocks FIRST — phase separation keeps W-gather
// hot in L2 during the pool phase; R1's pool/tnorm interleave thrashed L2:
// FETCH +62MB, WRITE +113MB, prep 103->131us). Single change vs R0: the
// 20-row gather loop is unrolled x4 (4 independent row loads in flight,
// accumulate kept in ascending-row order => bit-identical x).
// ---------------------------------------------------------------------------
__global__ __launch_bounds__(640) void prep_kernel(
    const int* __restrict__ ids, const float* __restrict__ W,
    const float* __restrict__ T,
    float* __restrict__ x, unsigned short* __restrict__ xh,
    float* __restrict__ rxn, unsigned short* __restrict__ Tb,
    u32* __restrict__ count)
{
    const int tid = threadIdx.x;
    const int w = tid >> 6, lane = tid & 63;
    if (blockIdx.x < POOL_BLOCKS) {
        // ----- pool path -----
        const int b = blockIdx.x;
        if (b == 0 && tid == 0) *count = 0;
        __shared__ int sid[SEQ];
        __shared__ float part[10 * 304];     // per-wave partial sums (12.2 KB)
        __shared__ float red[320];
        __shared__ float rns_s;
        for (int s = tid; s < SEQ; s += 640) sid[s] = ids[s * B_ + b];
        __syncthreads();
        // wave w owns rows s = w + j*10, j=0..19. Load 4 rows at a time for
        // MLP; accumulate sequentially in ascending j (bit-exact with R0).
        float4 a0 = make_float4(0.f, 0.f, 0.f, 0.f);
        float4 a1 = make_float4(0.f, 0.f, 0.f, 0.f);
        #pragma unroll
        for (int i = 0; i < 5; ++i) {
            const float4* W0 = (const float4*)(W + (size_t)sid[w + (4 * i + 0) * 10] * D_);
            const float4* W1 = (const float4*)(W + (size_t)sid[w + (4 * i + 1) * 10] * D_);
            const float4* W2 = (const float4*)(W + (size_t)sid[w + (4 * i + 2) * 10] * D_);
            const float4* W3 = (const float4*)(W + (size_t)sid[w + (4 * i + 3) * 10] * D_);
            float4 v0 = W0[lane];
            float4 v1 = W1[lane];
            float4 v2 = W2[lane];
            float4 v3 = W3[lane];
            a0.x += v0.x; a0.y += v0.y; a0.z += v0.z; a0.w += v0.w;
            a0.x += v1.x; a0.y += v1.y; a0.z += v1.z; a0.w += v1.w;
            a0.x += v2.x; a0.y += v2.y; a0.z += v2.z; a0.w += v2.w;
            a0.x += v3.x; a0.y += v3.y; a0.z += v3.z; a0.w += v3.w;
            if (lane < 11) {
                float4 q0 = W0[64 + lane];
                float4 q1 = W1[64 + lane];
                float4 q2 = W2[64 + lane];
                float4 q3 = W3[64 + lane];
                a1.x += q0.x; a1.y += q0.y; a1.z += q0.z; a1.w += q0.w;
                a1.x += q1.x; a1.y += q1.y; a1.z += q1.z; a1.w += q1.w;
                a1.x += q2.x; a1.y += q2.y; a1.z += q2.z; a1.w += q2.w;
                a1.x += q3.x; a1.y += q3.y; a1.z += q3.z; a1.w += q3.w;
            }
        }
        *(float4*)&part[w * 304 + lane * 4] = a0;              // dims 0..255
        if (lane < 11) *(float4*)&part[w * 304 + 256 + lane * 4] = a1;  // 256..299
        else if (lane == 11) {                                  // zero pad 300..303
            float4 z = make_float4(0.f, 0.f, 0.f, 0.f);
            *(float4*)&part[w * 304 + 256 + lane * 4] = z;
        }
        __syncthreads();
        float xv = 0.f;
        if (tid < 304) {
            float s = 0.f;
            #pragma unroll
            for (int ww = 0; ww < 10; ++ww) s += part[ww * 304 + tid];
            xv = s * (1.0f / SEQ);
        }
        if (tid < 320) red[tid] = (tid < D_) ? xv * xv : 0.f;
        __syncthreads();
        if (tid < 64) {
            float s = 0.f;
            #pragma unroll
            for (int i = 0; i < 5; ++i) s += red[tid + i * 64];
            #pragma unroll
            for (int m = 32; m >= 1; m >>= 1) s += __shfl_xor(s, m, 64);
            if (tid == 0) {
                float r = 1.0f / fmaxf(sqrtf(s), EPS);
                rxn[b] = r;
                rns_s = r;
            }
        }
        __syncthreads();
        const float rns = rns_s;
        if (tid < 320) {
            if (tid < D_) {
                x[(size_t)b * D_ + tid] = xv;
                xh[(size_t)b * DP + tid] = f2bf(xv * rns);
            } else {
                xh[(size_t)b * DP + tid] = 0;
            }
        }
    } else {
        // ----- tnorm/convert path: normalized bf16 rows (exact R0) -----
        const int n = (blockIdx.x - POOL_BLOCKS) * 10 + w;
        if (n >= NTP) return;
        ushort4* tb = (ushort4*)(Tb + (size_t)n * DP);   // 80 ushort4/row
        if (n >= NT) {
            ushort4 z = {0, 0, 0, 0};
            tb[lane] = z;
            if (lane < 16) tb[64 + lane] = z;
            return;
        }
        const float4* Tr = (const float4*)(T + (size_t)n * D_);
        float4 v = Tr[lane];
        float s = v.x * v.x + v.y * v.y + v.z * v.z + v.w * v.w;
        float4 w2 = make_float4(0.f, 0.f, 0.f, 0.f);
        if (lane < 11) {
            w2 = Tr[64 + lane];
            s += w2.x * w2.x + w2.y * w2.y + w2.z * w2.z + w2.w * w2.w;
        }
        #pragma unroll
        for (int m = 32; m >= 1; m >>= 1) s += __shfl_xor(s, m, 64);
        const float rns = 1.0f / fmaxf(sqrtf(s), EPS);
        ushort4 o;
        o.x = f2bf(v.x * rns); o.y = f2bf(v.y * rns);
        o.z = f2bf(v.z * rns); o.w = f2bf(v.w * rns);
        tb[lane] = o;
        if (lane < 16) {
            ushort4 p = {0, 0, 0, 0};
            if (lane < 11) {
                p.x = f2bf(w2.x * rns); p.y = f2bf(w2.y * rns);
                p.z = f2bf(w2.z * rns); p.w = f2bf(w2.w * rns);
            }
            tb[64 + lane] = p;
        }
    }
}

// ---------------------------------------------------------------------------
// K2: hh bf16 GEMM on normalized operands. 256x128 tile, 512 threads
// (8 waves, 4x2 of 64x64), launch_bounds(512,2) => 256-reg cap, NO spill.
// BK=64, global_load_lds width-16, xor-swizzled chunk pick. XCD swizzle:
// a strip's 4 M-blocks share g%8. Epilogue: float fmax, no atomics.
// ---------------------------------------------------------------------------
__global__ __launch_bounds__(512, 2) void gemm_hh_kernel(
    const unsigned short* __restrict__ Ah, const unsigned short* __restrict__ Tb,
    float* __restrict__ blockmax)
{
    __shared__ unsigned short sA[BM * BK];   // 32 KB
    __shared__ unsigned short sB[BN * BK];   // 16 KB
    __shared__ float sBestF[BM * 2];         // 2 KB

    const int tid = threadIdx.x;
    const int g = blockIdx.x;
    const int k8 = g & 7;
    const int h = g >> 3;
    const int bMi = h & 3;                       // M-tile (4)
    const int strip = ((h >> 2) << 3) | k8;      // same XCD for a strip's tiles

    const int lane = tid & 63, wid = tid >> 6;
    const int wm = wid >> 1, wn = wid & 1;       // 4 x 2 waves over 256 x 128
    const int quad = lane >> 4, l15 = lane & 15;

    const unsigned short* pA[4];
    int laA[4];
    #pragma unroll
    for (int j = 0; j < 4; ++j) {
        int L = (j * 8 + wid) * 64 + lane;       // 0..2047
        int r = L >> 3, c = (L & 7) ^ (r & 7);
        laA[j] = (j * 8 + wid) * 1024;
        pA[j] = Ah + (size_t)(bMi * BM + r) * DP + c * 8;
    }
    const unsigned short* pB[2];
    int laB[2];
    #pragma unroll
    for (int j = 0; j < 2; ++j) {
        int L = (j * 8 + wid) * 64 + lane;       // 0..1023
        int r = L >> 3, c = (L & 7) ^ (r & 7);
        laB[j] = (j * 8 + wid) * 1024;
        pB[j] = Tb + (size_t)(strip * BN + r) * DP + c * 8;
    }

    f32x4 acc[4][4] = {};

    for (int kp = 0; kp < DP; kp += BK) {
        #pragma unroll
        for (int j = 0; j < 4; ++j)
            gload_lds16(pA[j] + kp, (char*)sA + laA[j]);
        #pragma unroll
        for (int j = 0; j < 2; ++j)
            gload_lds16(pB[j] + kp, (char*)sB + laB[j]);
        __syncthreads();

        #pragma unroll
        for (int s = 0; s < 2; ++s) {
            bf16x8 fa[4], fb[4];
            #pragma unroll
            for (int f = 0; f < 4; ++f) {
                int ar = wm * 64 + f * 16 + l15;
                int ac = (s * 4 + quad) ^ (ar & 7);
                fa[f] = *(const bf16x8*)&sA[ar * BK + ac * 8];
                int br = wn * 64 + f * 16 + l15;
                int bc = (s * 4 + quad) ^ (br & 7);
                fb[f] = *(const bf16x8*)&sB[br * BK + bc * 8];
            }
            #pragma unroll
            for (int fm = 0; fm < 4; ++fm)
                #pragma unroll
                for (int fn = 0; fn < 4; ++fn)
                    acc[fm][fn] = __builtin_amdgcn_mfma_f32_16x16x32_bf16(
                        fa[fm], fb[fn], acc[fm][fn], 0, 0, 0);
        }
        __syncthreads();
    }

    // ---- epilogue: per-row fmax (acc is already the cosine), no atomics ----
    #pragma unroll
    for (int fm = 0; fm < 4; ++fm) {
        float v[4];
        #pragma unroll
        for (int r = 0; r < 4; ++r) {
            v[r] = fmaxf(fmaxf(acc[fm][0][r], acc[fm][1][r]),
                         fmaxf(acc[fm][2][r], acc[fm][3][r]));
        }
        #pragma unroll
        for (int m = 1; m < 16; m <<= 1) {
            #pragma unroll
            for (int r = 0; r < 4; ++r)
                v[r] = fmaxf(v[r], __shfl_xor(v[r], m, 64));
        }
        if (l15 == 0) {
            int rowbase = wm * 64 + fm * 16 + quad * 4;   // C row = quad*4+r
            #pragma unroll
            for (int r = 0; r < 4; ++r)
                sBestF[(rowbase + r) * 2 + wn] = v[r];
        }
    }
    __syncthreads();
    if (tid < BM)
        blockmax[(size_t)(bMi * BM + tid) * NSTRIP + strip] =
            fmaxf(sBestF[tid * 2], sBestF[tid * 2 + 1]);
}

// ---------------------------------------------------------------------------
// K3 "scan": per row, threshold = max(blockmax) - MARGIN; emit qualifying
// (row,strip) candidates; zero winner[row].
// ---------------------------------------------------------------------------
__global__ __launch_bounds__(256) void scan_kernel(
    const float* __restrict__ blockmax, u32* __restrict__ cand,
    u32* __restrict__ count, u64* __restrict__ winner)
{
    const int row = blockIdx.x;
    const int t = threadIdx.x;
    const int w = t >> 6, lane = t & 63;
    const float* bmr = blockmax + (size_t)row * NSTRIP;

    __shared__ float wred[4];
    __shared__ float thr_s;
    if (t == 0) winner[row] = 0ull;
    float m = -1e30f;
    for (int j = t; j < NSTRIP; j += 256) m = fmaxf(m, bmr[j]);
    #pragma unroll
    for (int msk = 32; msk >= 1; msk >>= 1) m = fmaxf(m, __shfl_xor(m, msk, 64));
    if (lane == 0) wred[w] = m;
    __syncthreads();
    if (t == 0) {
        float gmx = fmaxf(fmaxf(wred[0], wred[1]), fmaxf(wred[2], wred[3]));
        thr_s = gmx - MARGIN;
    }
    __syncthreads();
    const float thr = thr_s;
    for (int j = t; j < NSTRIP; j += 256) {
        if (bmr[j] >= thr) {
            u32 p = atomicAdd(count, 1u);
            if (p < CAND_MAX) cand[p] = ((u32)row << 10) | (u32)j;
        }
    }
}

// ---------------------------------------------------------------------------
// K4 "rescore": grid-stride over candidates; one block per candidate pass.
// Each wave: 16 cols concurrently (4 lanes/col), exact fp32; atomicMax winner.
// ---------------------------------------------------------------------------
__global__ __launch_bounds__(256) void rescore_kernel(
    const u32* __restrict__ cand, const u32* __restrict__ count,
    const float* __restrict__ x, const float* __restrict__ T,
    const float* __restrict__ rxn, u64* __restrict__ winner)
{
    u32 cnt = *count; if (cnt > CAND_MAX) cnt = CAND_MAX;
    __shared__ float4 xs4[75];
    const int t = threadIdx.x;
    const int w = t >> 6, lane = t & 63;
    const int lane4 = lane & 3, colw = lane >> 2;

    for (u32 ci = blockIdx.x; ci < cnt; ci += RESCORE_BLOCKS) {
        const u32 c = cand[ci];
        const int row = c >> 10, strip = c & 1023;
        __syncthreads();
        if (t < 75) xs4[t] = *(const float4*)&x[(size_t)row * D_ + t * 4];
        __syncthreads();
        const float rx = rxn[row];
        u64 best = 0ull;
        #pragma unroll
        for (int p = 0; p < 2; ++p) {
            const int n = strip * BN + w * 32 + p * 16 + colw;
            if (n < NT) {
                const float4* Tr = (const float4*)(T + (size_t)n * D_);
                float dot = 0.f, tt = 0.f;
                #pragma unroll
                for (int jj = 0; jj < 19; ++jj) {
                    int idx = lane4 + jj * 4;
                    if (idx < 75) {
                        float4 v = Tr[idx], xv = xs4[idx];
                        dot += v.x * xv.x + v.y * xv.y + v.z * xv.z + v.w * xv.w;
                        tt  += v.x * v.x + v.y * v.y + v.z * v.z + v.w * v.w;
                    }
                }
                dot += __shfl_xor(dot, 1, 64); tt += __shfl_xor(tt, 1, 64);
                dot += __shfl_xor(dot, 2, 64); tt += __shfl_xor(tt, 2, 64);
                float sim = dot * rx / fmaxf(sqrtf(tt), EPS);
                u64 pk = ((u64)simkey(sim) << 32) | (u32)(~n);
                best = (pk > best) ? pk : best;
            }
        }
        #pragma unroll
        for (int m = 1; m < 64; m <<= 1) {
            u64 o = __shfl_xor(best, m, 64);
            best = (o > best) ? o : best;
        }
        if (lane == 0 && best) atomicMax(&winner[row], best);
    }
}

// ---------------------------------------------------------------------------
// K5 "final": decode winner, fp64 rescore for score, label gather.
// ---------------------------------------------------------------------------
__global__ __launch_bounds__(64) void final_kernel(
    const u64* __restrict__ winner, const float* __restrict__ x,
    const float* __restrict__ T, const int* __restrict__ y_train,
    float* __restrict__ out)
{
    const int b = blockIdx.x;
    const int lane = threadIdx.x;
    int idx = (int)(~(u32)winner[b]);
    if (idx < 0 || idx >= NT) idx = 0;
    double dot = 0.0, nx = 0.0, nt = 0.0;
    for (int d = lane; d < D_; d += 64) {
        double xv = (double)x[(size_t)b * D_ + d];
        double tv = (double)T[(size_t)idx * D_ + d];
        dot += xv * tv; nx += xv * xv; nt += tv * tv;
    }
    #pragma unroll
    for (int m = 32; m >= 1; m >>= 1) {
        dot += __shfl_xor(dot, m, 64);
        nx  += __shfl_xor(nx, m, 64);
        nt  += __shfl_xor(nt, m, 64);
    }
    if (lane == 0) {
        double score = dot / (fmax(sqrt(nx), (double)EPS) * fmax(sqrt(nt), (double)EPS));
        out[b]      = (float)y_train[idx];
        out[B_ + b] = (float)score;
    }
}

// ---------------------------------------------------------------------------
extern "C" void kernel_launch(void* const* d_in, const int* in_sizes, int n_in,
                              void* d_out, int out_size, void* d_ws, size_t ws_size,
                              hipStream_t stream)
{
    const int*   ids = (const int*)d_in[0];
    const float* W   = (const float*)d_in[1];
    const float* T   = (const float*)d_in[2];
    const int*   y   = (const int*)d_in[3];

    char* ws = (char*)d_ws;
    size_t off = 0;
    float* x           = (float*)(ws + off);          off += (size_t)B_ * D_ * 4;        // 1,228,800
    unsigned short* xh = (unsigned short*)(ws + off); off += (size_t)B_ * DP * 2;        //   655,360
    float* rxn         = (float*)(ws + off);          off += (size_t)B_ * 4;             //     4,096
    unsigned short* Tb = (unsigned short*)(ws + off); off += (size_t)NTP * DP * 2;       // 64,225,280
    float* blockmax    = (float*)(ws + off);          off += (size_t)B_ * NSTRIP * 4;    //  3,211,264
    u32* cand          = (u32*)(ws + off);            off += (size_t)CAND_MAX * 4;       //     32,768
    u64* winner        = (u64*)(ws + off);            off += (size_t)B_ * 8;             //      8,192
    u32* count         = (u32*)(ws + off);            off += 256;                        // total ~69 MB

    prep_kernel<<<POOL_BLOCKS + TN_BLOCKS, 640, 0, stream>>>(ids, W, T, x, xh, rxn, Tb, count);
    gemm_hh_kernel<<<NSTRIP * 4, 512, 0, stream>>>(xh, Tb, blockmax);
    scan_kernel<<<B_, 256, 0, stream>>>(blockmax, cand, count, winner);
    rescore_kernel<<<RESCORE_BLOCKS, 256, 0, stream>>>(cand, count, x, T, rxn, winner);
    final_kernel<<<B_, 64, 0, stream>>>(winner, x, T, y, (float*)d_out);
}

// Round 4
// 372.667 us; speedup vs baseline: 1.0735x; 1.0735x over previous
//
#include <hip/hip_runtime.h>
#include <hip/hip_bf16.h>
#include <stdint.h>

#define EPS 1e-8f

typedef __attribute__((ext_vector_type(8))) short bf16x8;
typedef __attribute__((ext_vector_type(4))) float f32x4;
typedef unsigned long long u64;
typedef unsigned int u32;

constexpr int SEQ = 200;
constexpr int B_  = 1024;    // batch
constexpr int D_  = 300;     // embedding dim
constexpr int DP  = 320;     // K padded
constexpr int NT  = 100000;  // train rows
constexpr int BM = 256, BN = 128, BK = 64;
constexpr int NSTRIP = 784;            // N strips (128 wide), multiple of 8
constexpr int NTP = NSTRIP * BN;       // 100352 padded rows
constexpr int POOL_BLOCKS = B_;        // 1024
constexpr int TN2_BLOCKS = NTP / 8;    // 12544 (8 rows/block @ 512 thr)
constexpr int CAND_MAX = 8192;
constexpr int RESCORE_BLOCKS = 2048;
#define MARGIN 2e-3f

__device__ __forceinline__ unsigned short f2bf(float f) {   // RNE
    u32 b = __float_as_uint(f);
    return (unsigned short)((b + 0x7fffu + ((b >> 16) & 1u)) >> 16);
}
__device__ __forceinline__ u32 simkey(float s) {            // order-preserving
    u32 b = __float_as_uint(s);
    return (b & 0x80000000u) ? ~b : (b | 0x80000000u);
}
__device__ __forceinline__ void gload_lds16(const void* g, void* l) {
    __builtin_amdgcn_global_load_lds(
        (const __attribute__((address_space(1))) unsigned int*)g,
        (__attribute__((address_space(3))) unsigned int*)l, 16, 0, 0);
}

// ---------------------------------------------------------------------------
// K1a "pool": EXACT R0 pool path (serial gather loop — R1/R2 showed both the
// x4 MLP unroll and pool/tnorm interleave regress it; the gather sits at an
// L3/fabric equilibrium ~3.5 TB/s). Split from tnorm for per-stage rocprof
// visibility. 1024 blocks x 640 thr.
// ---------------------------------------------------------------------------
__global__ __launch_bounds__(640) void pool_kernel(
    const int* __restrict__ ids, const float* __restrict__ W,
    float* __restrict__ x, unsigned short* __restrict__ xh,
    float* __restrict__ rxn, u32* __restrict__ count)
{
    const int tid = threadIdx.x;
    const int w = tid >> 6, lane = tid & 63;
    const int b = blockIdx.x;
    if (b == 0 && tid == 0) *count = 0;
    __shared__ int sid[SEQ];
    __shared__ float part[10 * 304];     // per-wave partial sums (12.2 KB)
    __shared__ float red[320];
    __shared__ float rns_s;
    for (int s = tid; s < SEQ; s += 640) sid[s] = ids[s * B_ + b];
    __syncthreads();
    float4 a0 = make_float4(0.f, 0.f, 0.f, 0.f);
    float4 a1 = make_float4(0.f, 0.f, 0.f, 0.f);
    for (int s = w; s < SEQ; s += 10) {
        const float4* Wr = (const float4*)(W + (size_t)sid[s] * D_);
        float4 v = Wr[lane];
        a0.x += v.x; a0.y += v.y; a0.z += v.z; a0.w += v.w;
        if (lane < 11) {
            float4 u = Wr[64 + lane];
            a1.x += u.x; a1.y += u.y; a1.z += u.z; a1.w += u.w;
        }
    }
    *(float4*)&part[w * 304 + lane * 4] = a0;              // dims 0..255
    if (lane < 11) *(float4*)&part[w * 304 + 256 + lane * 4] = a1;  // 256..299
    else if (lane == 11) {                                  // zero pad 300..303
        float4 z = make_float4(0.f, 0.f, 0.f, 0.f);
        *(float4*)&part[w * 304 + 256 + lane * 4] = z;
    }
    __syncthreads();
    float xv = 0.f;
    if (tid < 304) {
        float s = 0.f;
        #pragma unroll
        for (int ww = 0; ww < 10; ++ww) s += part[ww * 304 + tid];
        xv = s * (1.0f / SEQ);
    }
    if (tid < 320) red[tid] = (tid < D_) ? xv * xv : 0.f;
    __syncthreads();
    if (tid < 64) {
        float s = 0.f;
        #pragma unroll
        for (int i = 0; i < 5; ++i) s += red[tid + i * 64];
        #pragma unroll
        for (int m = 32; m >= 1; m >>= 1) s += __shfl_xor(s, m, 64);
        if (tid == 0) {
            float r = 1.0f / fmaxf(sqrtf(s), EPS);
            rxn[b] = r;
            rns_s = r;
        }
    }
    __syncthreads();
    const float rns = rns_s;
    if (tid < 320) {
        if (tid < D_) {
            x[(size_t)b * D_ + tid] = xv;
            xh[(size_t)b * DP + tid] = f2bf(xv * rns);
        } else {
            xh[(size_t)b * DP + tid] = 0;
        }
    }
}

// ---------------------------------------------------------------------------
// K1b "tnorm": per-row normalize+bf16 convert. Per-row code EXACTLY R0's
// (each wave owns one row; rows fully independent => re-blocking changes no
// arithmetic). 512 thr (8 waves = 2/SIMD) packs 4 blocks/CU = 32 waves vs
// 640-thr's 2 blocks (the 3/3/2/2 SIMD packing capped 640-thr at 20 waves).
// ---------------------------------------------------------------------------
__global__ __launch_bounds__(512) void tnorm_kernel(
    const float* __restrict__ T, unsigned short* __restrict__ Tb)
{
    const int tid = threadIdx.x;
    const int w = tid >> 6, lane = tid & 63;
    const int n = blockIdx.x * 8 + w;
    if (n >= NTP) return;
    ushort4* tb = (ushort4*)(Tb + (size_t)n * DP);   // 80 ushort4/row
    if (n >= NT) {
        ushort4 z = {0, 0, 0, 0};
        tb[lane] = z;
        if (lane < 16) tb[64 + lane] = z;
        return;
    }
    const float4* Tr = (const float4*)(T + (size_t)n * D_);
    float4 v = Tr[lane];
    float s = v.x * v.x + v.y * v.y + v.z * v.z + v.w * v.w;
    float4 w2 = make_float4(0.f, 0.f, 0.f, 0.f);
    if (lane < 11) {
        w2 = Tr[64 + lane];
        s += w2.x * w2.x + w2.y * w2.y + w2.z * w2.z + w2.w * w2.w;
    }
    #pragma unroll
    for (int m = 32; m >= 1; m >>= 1) s += __shfl_xor(s, m, 64);
    const float rns = 1.0f / fmaxf(sqrtf(s), EPS);
    ushort4 o;
    o.x = f2bf(v.x * rns); o.y = f2bf(v.y * rns);
    o.z = f2bf(v.z * rns); o.w = f2bf(v.w * rns);
    tb[lane] = o;
    if (lane < 16) {
        ushort4 p = {0, 0, 0, 0};
        if (lane < 11) {
            p.x = f2bf(w2.x * rns); p.y = f2bf(w2.y * rns);
            p.z = f2bf(w2.z * rns); p.w = f2bf(w2.w * rns);
        }
        tb[64 + lane] = p;
    }
}

// ---------------------------------------------------------------------------
// K2: hh bf16 GEMM on normalized operands. 256x128 tile, 512 threads
// (8 waves, 4x2 of 64x64), launch_bounds(512,2) => 256-reg cap, NO spill.
// BK=64, global_load_lds width-16, xor-swizzled chunk pick. XCD swizzle:
// a strip's 4 M-blocks share g%8. Epilogue: float fmax, no atomics.
// ---------------------------------------------------------------------------
__global__ __launch_bounds__(512, 2) void gemm_hh_kernel(
    const unsigned short* __restrict__ Ah, const unsigned short* __restrict__ Tb,
    float* __restrict__ blockmax)
{
    __shared__ unsigned short sA[BM * BK];   // 32 KB
    __shared__ unsigned short sB[BN * BK];   // 16 KB
    __shared__ float sBestF[BM * 2];         // 2 KB

    const int tid = threadIdx.x;
    const int g = blockIdx.x;
    const int k8 = g & 7;
    const int h = g >> 3;
    const int bMi = h & 3;                       // M-tile (4)
    const int strip = ((h >> 2) << 3) | k8;      // same XCD for a strip's tiles

    const int lane = tid & 63, wid = tid >> 6;
    const int wm = wid >> 1, wn = wid & 1;       // 4 x 2 waves over 256 x 128
    const int quad = lane >> 4, l15 = lane & 15;

    const unsigned short* pA[4];
    int laA[4];
    #pragma unroll
    for (int j = 0; j < 4; ++j) {
        int L = (j * 8 + wid) * 64 + lane;       // 0..2047
        int r = L >> 3, c = (L & 7) ^ (r & 7);
        laA[j] = (j * 8 + wid) * 1024;
        pA[j] = Ah + (size_t)(bMi * BM + r) * DP + c * 8;
    }
    const unsigned short* pB[2];
    int laB[2];
    #pragma unroll
    for (int j = 0; j < 2; ++j) {
        int L = (j * 8 + wid) * 64 + lane;       // 0..1023
        int r = L >> 3, c = (L & 7) ^ (r & 7);
        laB[j] = (j * 8 + wid) * 1024;
        pB[j] = Tb + (size_t)(strip * BN + r) * DP + c * 8;
    }

    f32x4 acc[4][4] = {};

    for (int kp = 0; kp < DP; kp += BK) {
        #pragma unroll
        for (int j = 0; j < 4; ++j)
            gload_lds16(pA[j] + kp, (char*)sA + laA[j]);
        #pragma unroll
        for (int j = 0; j < 2; ++j)
            gload_lds16(pB[j] + kp, (char*)sB + laB[j]);
        __syncthreads();

        #pragma unroll
        for (int s = 0; s < 2; ++s) {
            bf16x8 fa[4], fb[4];
            #pragma unroll
            for (int f = 0; f < 4; ++f) {
                int ar = wm * 64 + f * 16 + l15;
                int ac = (s * 4 + quad) ^ (ar & 7);
                fa[f] = *(const bf16x8*)&sA[ar * BK + ac * 8];
                int br = wn * 64 + f * 16 + l15;
                int bc = (s * 4 + quad) ^ (br & 7);
                fb[f] = *(const bf16x8*)&sB[br * BK + bc * 8];
            }
            #pragma unroll
            for (int fm = 0; fm < 4; ++fm)
                #pragma unroll
                for (int fn = 0; fn < 4; ++fn)
                    acc[fm][fn] = __builtin_amdgcn_mfma_f32_16x16x32_bf16(
                        fa[fm], fb[fn], acc[fm][fn], 0, 0, 0);
        }
        __syncthreads();
    }

    // ---- epilogue: per-row fmax (acc is already the cosine), no atomics ----
    #pragma unroll
    for (int fm = 0; fm < 4; ++fm) {
        float v[4];
        #pragma unroll
        for (int r = 0; r < 4; ++r) {
            v[r] = fmaxf(fmaxf(acc[fm][0][r], acc[fm][1][r]),
                         fmaxf(acc[fm][2][r], acc[fm][3][r]));
        }
        #pragma unroll
        for (int m = 1; m < 16; m <<= 1) {
            #pragma unroll
            for (int r = 0; r < 4; ++r)
                v[r] = fmaxf(v[r], __shfl_xor(v[r], m, 64));
        }
        if (l15 == 0) {
            int rowbase = wm * 64 + fm * 16 + quad * 4;   // C row = quad*4+r
            #pragma unroll
            for (int r = 0; r < 4; ++r)
                sBestF[(rowbase + r) * 2 + wn] = v[r];
        }
    }
    __syncthreads();
    if (tid < BM)
        blockmax[(size_t)(bMi * BM + tid) * NSTRIP + strip] =
            fmaxf(sBestF[tid * 2], sBestF[tid * 2 + 1]);
}

// ---------------------------------------------------------------------------
// K3 "scan": per row, threshold = max(blockmax) - MARGIN; emit qualifying
// (row,strip) candidates; zero winner[row].
// ---------------------------------------------------------------------------
__global__ __launch_bounds__(256) void scan_kernel(
    const float* __restrict__ blockmax, u32* __restrict__ cand,
    u32* __restrict__ count, u64* __restrict__ winner)
{
    const int row = blockIdx.x;
    const int t = threadIdx.x;
    const int w = t >> 6, lane = t & 63;
    const float* bmr = blockmax + (size_t)row * NSTRIP;

    __shared__ float wred[4];
    __shared__ float thr_s;
    if (t == 0) winner[row] = 0ull;
    float m = -1e30f;
    for (int j = t; j < NSTRIP; j += 256) m = fmaxf(m, bmr[j]);
    #pragma unroll
    for (int msk = 32; msk >= 1; msk >>= 1) m = fmaxf(m, __shfl_xor(m, msk, 64));
    if (lane == 0) wred[w] = m;
    __syncthreads();
    if (t == 0) {
        float gmx = fmaxf(fmaxf(wred[0], wred[1]), fmaxf(wred[2], wred[3]));
        thr_s = gmx - MARGIN;
    }
    __syncthreads();
    const float thr = thr_s;
    for (int j = t; j < NSTRIP; j += 256) {
        if (bmr[j] >= thr) {
            u32 p = atomicAdd(count, 1u);
            if (p < CAND_MAX) cand[p] = ((u32)row << 10) | (u32)j;
        }
    }
}

// ---------------------------------------------------------------------------
// K4 "rescore": grid-stride over candidates; one block per candidate pass.
// Each wave: 16 cols concurrently (4 lanes/col), exact fp32; atomicMax winner.
// ---------------------------------------------------------------------------
__global__ __launch_bounds__(256) void rescore_kernel(
    const u32* __restrict__ cand, const u32* __restrict__ count,
    const float* __restrict__ x, const float* __restrict__ T,
    const float* __restrict__ rxn, u64* __restrict__ winner)
{
    u32 cnt = *count; if (cnt > CAND_MAX) cnt = CAND_MAX;
    __shared__ float4 xs4[75];
    const int t = threadIdx.x;
    const int w = t >> 6, lane = t & 63;
    const int lane4 = lane & 3, colw = lane >> 2;

    for (u32 ci = blockIdx.x; ci < cnt; ci += RESCORE_BLOCKS) {
        const u32 c = cand[ci];
        const int row = c >> 10, strip = c & 1023;
        __syncthreads();
        if (t < 75) xs4[t] = *(const float4*)&x[(size_t)row * D_ + t * 4];
        __syncthreads();
        const float rx = rxn[row];
        u64 best = 0ull;
        #pragma unroll
        for (int p = 0; p < 2; ++p) {
            const int n = strip * BN + w * 32 + p * 16 + colw;
            if (n < NT) {
                const float4* Tr = (const float4*)(T + (size_t)n * D_);
                float dot = 0.f, tt = 0.f;
                #pragma unroll
                for (int jj = 0; jj < 19; ++jj) {
                    int idx = lane4 + jj * 4;
                    if (idx < 75) {
                        float4 v = Tr[idx], xv = xs4[idx];
                        dot += v.x * xv.x + v.y * xv.y + v.z * xv.z + v.w * xv.w;
                        tt  += v.x * v.x + v.y * v.y + v.z * v.z + v.w * v.w;
                    }
                }
                dot += __shfl_xor(dot, 1, 64); tt += __shfl_xor(tt, 1, 64);
                dot += __shfl_xor(dot, 2, 64); tt += __shfl_xor(tt, 2, 64);
                float sim = dot * rx / fmaxf(sqrtf(tt), EPS);
                u64 pk = ((u64)simkey(sim) << 32) | (u32)(~n);
                best = (pk > best) ? pk : best;
            }
        }
        #pragma unroll
        for (int m = 1; m < 64; m <<= 1) {
            u64 o = __shfl_xor(best, m, 64);
            best = (o > best) ? o : best;
        }
        if (lane == 0 && best) atomicMax(&winner[row], best);
    }
}

// ---------------------------------------------------------------------------
// K5 "final": decode winner, fp64 rescore for score, label gather.
// ---------------------------------------------------------------------------
__global__ __launch_bounds__(64) void final_kernel(
    const u64* __restrict__ winner, const float* __restrict__ x,
    const float* __restrict__ T, const int* __restrict__ y_train,
    float* __restrict__ out)
{
    const int b = blockIdx.x;
    const int lane = threadIdx.x;
    int idx = (int)(~(u32)winner[b]);
    if (idx < 0 || idx >= NT) idx = 0;
    double dot = 0.0, nx = 0.0, nt = 0.0;
    for (int d = lane; d < D_; d += 64) {
        double xv = (double)x[(size_t)b * D_ + d];
        double tv = (double)T[(size_t)idx * D_ + d];
        dot += xv * tv; nx += xv * xv; nt += tv * tv;
    }
    #pragma unroll
    for (int m = 32; m >= 1; m >>= 1) {
        dot += __shfl_xor(dot, m, 64);
        nx  += __shfl_xor(nx, m, 64);
        nt  += __shfl_xor(nt, m, 64);
    }
    if (lane == 0) {
        double score = dot / (fmax(sqrt(nx), (double)EPS) * fmax(sqrt(nt), (double)EPS));
        out[b]      = (float)y_train[idx];
        out[B_ + b] = (float)score;
    }
}

// ---------------------------------------------------------------------------
extern "C" void kernel_launch(void* const* d_in, const int* in_sizes, int n_in,
                              void* d_out, int out_size, void* d_ws, size_t ws_size,
                              hipStream_t stream)
{
    const int*   ids = (const int*)d_in[0];
    const float* W   = (const float*)d_in[1];
    const float* T   = (const float*)d_in[2];
    const int*   y   = (const int*)d_in[3];

    char* ws = (char*)d_ws;
    size_t off = 0;
    float* x           = (float*)(ws + off);          off += (size_t)B_ * D_ * 4;        // 1,228,800
    unsigned short* xh = (unsigned short*)(ws + off); off += (size_t)B_ * DP * 2;        //   655,360
    float* rxn         = (float*)(ws + off);          off += (size_t)B_ * 4;             //     4,096
    unsigned short* Tb = (unsigned short*)(ws + off); off += (size_t)NTP * DP * 2;       // 64,225,280
    float* blockmax    = (float*)(ws + off);          off += (size_t)B_ * NSTRIP * 4;    //  3,211,264
    u32* cand          = (u32*)(ws + off);            off += (size_t)CAND_MAX * 4;       //     32,768
    u64* winner        = (u64*)(ws + off);            off += (size_t)B_ * 8;             //      8,192
    u32* count         = (u32*)(ws + off);            off += 256;                        // total ~69 MB

    pool_kernel<<<POOL_BLOCKS, 640, 0, stream>>>(ids, W, x, xh, rxn, count);
    tnorm_kernel<<<TN2_BLOCKS, 512, 0, stream>>>(T, Tb);
    gemm_hh_kernel<<<NSTRIP * 4, 512, 0, stream>>>(xh, Tb, blockmax);
    scan_kernel<<<B_, 256, 0, stream>>>(blockmax, cand, count, winner);
    rescore_kernel<<<RESCORE_BLOCKS, 256, 0, stream>>>(cand, count, x, T, rxn, winner);
    final_kernel<<<B_, 64, 0, stream>>>(winner, x, T, y, (float*)d_out);
}